// Round 1
// baseline (72388.110 us; speedup 1.0000x reference)
//
#include <hip/hip_runtime.h>
#include <cstdint>
#include <cstddef>

#define NWG 64
#define NTHR 512
#define TSTEPS 16384
#define HDIM 1024
#define EDIM 13
#define HLDIM 512

// ---------------------------------------------------------------------------
// Init kernel: re-arm flags and seed h-buffer parity 0 with h0 every call
// (d_ws is poisoned once with 0xAA and NOT re-poisoned between graph replays,
//  so the persistent kernel must be re-armed by us each launch).
// ---------------------------------------------------------------------------
__global__ void k_init(const float* __restrict__ h0, float* __restrict__ hbuf,
                       int* __restrict__ flags) {
  int t = threadIdx.x;
  if (t < NWG) flags[t] = 0;
  if (t < HDIM) hbuf[t] = h0[t];
}

// ---------------------------------------------------------------------------
// Persistent LSTM kernel. 64 WGs x 512 threads, one WG per CU.
// WG w owns hidden units [16w, 16w+16) -> 64 gate rows of W_hh held in VGPRs
// (128 floats/thread). Cross-WG sync: per-WG flags + double-buffered h in
// global memory, all cross-WG data moved with agent-scope atomics (sc0/sc1
// -> coherent at MALL, immune to non-coherent per-XCD L2s).
// ---------------------------------------------------------------------------
__global__ __launch_bounds__(NTHR) void k_main(
    const float* __restrict__ x, const float* __restrict__ c0,
    const float* __restrict__ Wih, const float* __restrict__ Whh,
    const float* __restrict__ bih, const float* __restrict__ bhh,
    const float* __restrict__ W1, const float* __restrict__ b1,
    const float* __restrict__ W2, const float* __restrict__ b2,
    float* __restrict__ out, int* flags, float* hbuf, float* ubuf) {
  const int w = blockIdx.x;
  const int tid = threadIdx.x;
  const int sub = tid & 7;    // col-chunk index within row (8 x 128 cols)
  const int row = tid >> 3;   // local gate row 0..63 (unit-major: row = 4*lu+g)
  const int wave = tid >> 6;  // 0..7
  const int lane = tid & 63;
  const int g = row & 3;      // 0=i 1=f 2=g 3=o
  const int lu = row >> 2;    // local unit 0..15
  const int grow = g * HDIM + w * 16 + lu;  // global gate row (gate-major stack)

  __shared__ float4 lds_h4[HDIM / 4];
  __shared__ float lds_wih[64][17];  // stride 17: conflict-free owner reads
  __shared__ float lds_bsum[64];
  __shared__ float lds_x[16];
  __shared__ float lds_r0[8], lds_r1[8];
  float* lds_h = (float*)lds_h4;

  // ---- persist this thread's W_hh chunk in registers, rotated chunk order
  // so that at compute time the wave's 8 distinct LDS b128 addresses land on
  // 8 disjoint 4-bank groups (conflict-free; same-address lanes broadcast).
  float4 wreg[32];
  const float4* wrow = (const float4*)(Whh + (size_t)grow * HDIM) + sub * 32;
#pragma unroll
  for (int i = 0; i < 32; ++i) wreg[i] = wrow[(i + sub) & 31];

  if (tid < 64) {
    int g2 = tid & 3, lu2 = tid >> 2;
    int gr2 = g2 * HDIM + w * 16 + lu2;
#pragma unroll
    for (int e = 0; e < EDIM; ++e) lds_wih[tid][e] = Wih[gr2 * EDIM + e];
    lds_bsum[tid] = bih[gr2] + bhh[gr2];
  }
  // cell state: lanes 0 and 32 of each wave own units 2*wave and 2*wave+1
  float cst = c0[w * 16 + 2 * wave + (lane >> 5)];
  __syncthreads();

  const float gsc = (g == 2) ? 2.f : 1.f;  // tanh via 2*sigmoid(2x)-1

  for (int t = 1; t <= TSTEPS; ++t) {
    float* hprev = hbuf + ((t - 1) & 1) * HDIM;
    float* hcur = hbuf + (t & 1) * HDIM;

    // ---- wait until every WG published h_{t-1}
    if (wave == 0) {
      while (__hip_atomic_load(&flags[lane], __ATOMIC_RELAXED,
                               __HIP_MEMORY_SCOPE_AGENT) < t - 1) {
      }
    }
    __syncthreads();

    // ---- fetch fresh h_{t-1} (coherent) + x_{t-1} into LDS
    float a0 = __hip_atomic_load(&hprev[tid], __ATOMIC_RELAXED,
                                 __HIP_MEMORY_SCOPE_AGENT);
    float a1 = __hip_atomic_load(&hprev[NTHR + tid], __ATOMIC_RELAXED,
                                 __HIP_MEMORY_SCOPE_AGENT);
    if (tid < EDIM) lds_x[tid] = x[(size_t)(t - 1) * EDIM + tid];
    lds_h[tid] = a0;
    lds_h[NTHR + tid] = a1;
    __syncthreads();

    // ---- gate pre-activation: x-projection folded into the same reduction
    float acc = lds_wih[row][sub] * lds_x[sub];
    if (sub < EDIM - 8) acc += lds_wih[row][sub + 8] * lds_x[sub + 8];
    if (sub == 0) acc += lds_bsum[row];
#pragma unroll
    for (int i = 0; i < 32; ++i) {
      float4 hv = lds_h4[sub * 32 + ((i + sub) & 31)];
      float4 wv = wreg[i];
      acc += wv.x * hv.x;
      acc += wv.y * hv.y;
      acc += wv.z * hv.z;
      acc += wv.w * hv.w;
    }
    acc += __shfl_xor(acc, 1);
    acc += __shfl_xor(acc, 2);
    acc += __shfl_xor(acc, 4);

    // ---- activations computed in parallel on all lanes (one exp chain)
    float e = __expf(-gsc * acc);
    float y = 1.f / (1.f + e);
    float act = (g == 2) ? 2.f * y - 1.f : y;

    int base = lane & 32;
    float ai = __shfl(act, base + 0);
    float af = __shfl(act, base + 8);
    float ag = __shfl(act, base + 16);
    float ao = __shfl(act, base + 24);
    if ((lane & 31) == 0) {
      cst = af * cst + ai * ag;
      float e2 = __expf(-2.f * cst);
      float hn = ao * (2.f / (1.f + e2) - 1.f);
      __hip_atomic_store(&hcur[w * 16 + 2 * wave + (lane >> 5)], hn,
                         __ATOMIC_RELAXED, __HIP_MEMORY_SCOPE_AGENT);
    }
    // barrier drains every wave's vmcnt (stores performed at coherent point)
    __syncthreads();
    if (tid == 0)
      __hip_atomic_store(&flags[w], t, __ATOMIC_RELEASE,
                         __HIP_MEMORY_SCOPE_AGENT);
  }

  // ---- tail step 1: u = tanh(W1 @ h_T + b1), 8 rows per WG --------------
  if (wave == 0) {
    while (__hip_atomic_load(&flags[lane], __ATOMIC_RELAXED,
                             __HIP_MEMORY_SCOPE_AGENT) < TSTEPS) {
    }
  }
  __syncthreads();
  {
    // h_T lives in parity (TSTEPS & 1) == 0
    float a0 = __hip_atomic_load(&hbuf[tid], __ATOMIC_RELAXED,
                                 __HIP_MEMORY_SCOPE_AGENT);
    float a1 = __hip_atomic_load(&hbuf[NTHR + tid], __ATOMIC_RELAXED,
                                 __HIP_MEMORY_SCOPE_AGENT);
    lds_h[tid] = a0;
    lds_h[NTHR + tid] = a1;
  }
  __syncthreads();
  {
    int r1 = 8 * w + wave;  // one MLP row per wave
    const float* w1p = W1 + (size_t)r1 * HDIM + lane * 16;
    float acc1 = 0.f;
#pragma unroll
    for (int i = 0; i < 16; ++i) acc1 += w1p[i] * lds_h[lane * 16 + i];
#pragma unroll
    for (int m = 1; m < 64; m <<= 1) acc1 += __shfl_xor(acc1, m);
    if (lane == 0) {
      float e2 = __expf(-2.f * (acc1 + b1[r1]));
      float u = 2.f / (1.f + e2) - 1.f;
      __hip_atomic_store(&ubuf[r1], u, __ATOMIC_RELAXED,
                         __HIP_MEMORY_SCOPE_AGENT);
    }
  }
  __syncthreads();
  if (tid == 0)
    __hip_atomic_store(&flags[w], TSTEPS + 1, __ATOMIC_RELEASE,
                       __HIP_MEMORY_SCOPE_AGENT);

  // ---- tail step 2: out = W2 @ u + b2, WG 0 only -------------------------
  if (w == 0) {
    if (wave == 0) {
      while (__hip_atomic_load(&flags[lane], __ATOMIC_RELAXED,
                               __HIP_MEMORY_SCOPE_AGENT) < TSTEPS + 1) {
      }
    }
    __syncthreads();
    float uv = __hip_atomic_load(&ubuf[tid], __ATOMIC_RELAXED,
                                 __HIP_MEMORY_SCOPE_AGENT);
    float p0 = W2[tid] * uv;
    float p1 = W2[HLDIM + tid] * uv;
#pragma unroll
    for (int m = 1; m < 64; m <<= 1) {
      p0 += __shfl_xor(p0, m);
      p1 += __shfl_xor(p1, m);
    }
    if (lane == 0) {
      lds_r0[wave] = p0;
      lds_r1[wave] = p1;
    }
    __syncthreads();
    if (tid == 0) {
      float o0 = b2[0], o1 = b2[1];
#pragma unroll
      for (int k = 0; k < 8; ++k) {
        o0 += lds_r0[k];
        o1 += lds_r1[k];
      }
      out[0] = o0;
      out[1] = o1;
    }
  }
}

extern "C" void kernel_launch(void* const* d_in, const int* in_sizes, int n_in,
                              void* d_out, int out_size, void* d_ws,
                              size_t ws_size, hipStream_t stream) {
  const float* x = (const float*)d_in[0];
  const float* h0 = (const float*)d_in[1];
  const float* c0 = (const float*)d_in[2];
  const float* Wih = (const float*)d_in[3];
  const float* Whh = (const float*)d_in[4];
  const float* bih = (const float*)d_in[5];
  const float* bhh = (const float*)d_in[6];
  const float* W1 = (const float*)d_in[7];
  const float* b1 = (const float*)d_in[8];
  const float* W2 = (const float*)d_in[9];
  const float* b2 = (const float*)d_in[10];
  float* out = (float*)d_out;

  int* flags = (int*)d_ws;
  float* hbuf = (float*)((char*)d_ws + 256);
  float* ubuf = (float*)((char*)d_ws + 256 + 2 * HDIM * sizeof(float));

  k_init<<<1, 1024, 0, stream>>>(h0, hbuf, flags);
  k_main<<<NWG, NTHR, 0, stream>>>(x, c0, Wih, Whh, bih, bhh, W1, b1, W2, b2,
                                   out, flags, hbuf, ubuf);
}

// Round 3
// 51618.274 us; speedup vs baseline: 1.4024x; 1.4024x over previous
//
#include <hip/hip_runtime.h>
#include <cstdint>
#include <cstddef>

#define NWG 64
#define NTHR 512
#define TSTEPS 16384
#define HDIM 1024
#define EDIM 13
#define HLDIM 512

typedef unsigned long long ull;

// ---------------------------------------------------------------------------
// Init kernel: re-arm the tagged h-record ring and u-record every call (d_ws
// is poisoned once with 0xAA and never re-poisoned between graph replays; the
// poison pattern would read as a huge bogus tag, and a finished replay leaves
// end-state tags behind, so every tag word must be rewritten each launch).
// hrec[parity][i] = { low32: f32 h value, high32: u32 step tag }, 4 parities.
// Parity 0 seeded with h0 at tag 0; other parities tag 0 (never a valid want
// for those parities: parity p only ever wants tags ≡ p (mod 4), p != 0).
// ---------------------------------------------------------------------------
__global__ void k_init(const float* __restrict__ h0, ull* __restrict__ hrec,
                       ull* __restrict__ urec) {
  int i = threadIdx.x;
  hrec[i] = (ull)__float_as_uint(h0[i]);  // {h0, tag=0}
  hrec[HDIM + i] = 0ull;
  hrec[2 * HDIM + i] = 0ull;
  hrec[3 * HDIM + i] = 0ull;
  if (i < HLDIM) urec[i] = 0ull;
}

// ---------------------------------------------------------------------------
// Persistent LSTM kernel. 64 WGs x 512 threads, one WG per CU.
// WG w owns hidden units [16w, 16w+16) -> 64 gate rows of W_hh pinned in
// VGPRs (128 floats/thread, asm-pinned so the compiler cannot rematerialize;
// round-1 failure mode: VGPR_Count=96 -> W re-streamed from L2 every step).
// Cross-WG sync: each hidden unit is a self-validating {value, tag} 8-byte
// chunk in a 4-deep parity ring, moved with relaxed agent-scope 64-bit
// atomics (single-copy atomic, serviced at the coherent point -> immune to
// non-coherent per-XCD L2s). One MALL round trip + one __syncthreads a step.
// ---------------------------------------------------------------------------
__global__ __launch_bounds__(NTHR, 2) void k_main(
    const float* __restrict__ x, const float* __restrict__ c0,
    const float* __restrict__ Wih, const float* __restrict__ Whh,
    const float* __restrict__ bih, const float* __restrict__ bhh,
    const float* __restrict__ W1, const float* __restrict__ b1,
    const float* __restrict__ W2, const float* __restrict__ b2,
    float* __restrict__ out, ull* hrec, ull* urec) {
  const int w = blockIdx.x;
  const int tid = threadIdx.x;
  const int sub = tid & 7;    // col-chunk index within row (8 x 128 cols)
  const int row = tid >> 3;   // local gate row 0..63
  const int wave = tid >> 6;  // 0..7
  const int lane = tid & 63;
  const int g = row & 3;      // 0=i 1=f 2=g 3=o
  const int lu = row >> 2;    // local unit 0..15
  const int grow = g * HDIM + w * 16 + lu;  // global gate row (gate-major)

  __shared__ float4 lds_h4[2][HDIM / 4];  // double-buffered by step parity
  __shared__ float lds_x[2][16];
  __shared__ float lds_wih[64][17];  // stride 17: conflict-free owner reads
  __shared__ float lds_bsum[64];
  __shared__ float lds_r0[8], lds_r1[8];
  float* lds_hf = (float*)lds_h4;  // [2][1024] flat

  // ---- load this thread's W_hh chunk, rotated so the wave's 8 distinct LDS
  // b128 addresses at compute time cover all 32 banks (conflict-free).
  float4 wreg[32];
  const float4* wrow = (const float4*)(Whh + (size_t)grow * HDIM) + sub * 32;
#pragma unroll
  for (int i = 0; i < 32; ++i) wreg[i] = wrow[(i + sub) & 31];
  // Pin in VGPRs: the asm claims to rewrite each value, so the compiler can
  // no longer fold the loads back into the step loop.
#pragma unroll
  for (int i = 0; i < 32; ++i)
    asm volatile("" : "+v"(wreg[i].x), "+v"(wreg[i].y), "+v"(wreg[i].z),
                     "+v"(wreg[i].w));

  if (tid < 64) {
    int g2 = tid & 3, lu2 = tid >> 2;
    int gr2 = g2 * HDIM + w * 16 + lu2;
#pragma unroll
    for (int e = 0; e < EDIM; ++e) lds_wih[tid][e] = Wih[gr2 * EDIM + e];
    lds_bsum[tid] = bih[gr2] + bhh[gr2];
  }
  // cell state: lanes 0 and 32 of each wave own units 2*wave and 2*wave+1
  float cst = c0[w * 16 + 2 * wave + (lane >> 5)];
  __syncthreads();

  const float gsc = (g == 2) ? 2.f : 1.f;  // tanh via 2*sigmoid(2x)-1

  for (int t = 1; t <= TSTEPS; ++t) {
    const int lp = (t - 1) & 1;  // LDS parity (2-deep, barrier-separated)
    // ---- x_t prefetch: issue before the poll so its latency hides there
    float xv = 0.f;
    if (tid < EDIM) xv = x[(size_t)(t - 1) * EDIM + tid];

    // ---- poll this thread's two {h, tag} chunks of h_{t-1}; the poll load
    // IS the data load (one MALL round trip). 4-deep ring: overwrite of a
    // tag-t chunk (by tag t+4) needs three cross-WG dependence chains of
    // separation -> overwrite-before-read unreachable.
    const ull* src = hrec + (size_t)((t - 1) & 3) * HDIM;
    const unsigned want = (unsigned)(t - 1);
    ull v0 = __hip_atomic_load(&src[tid], __ATOMIC_RELAXED,
                               __HIP_MEMORY_SCOPE_AGENT);
    ull v1 = __hip_atomic_load(&src[tid + NTHR], __ATOMIC_RELAXED,
                               __HIP_MEMORY_SCOPE_AGENT);
    for (;;) {
      bool b0 = (unsigned)(v0 >> 32) == want;
      bool b1 = (unsigned)(v1 >> 32) == want;
      if (b0 && b1) break;
      if (!b0)
        v0 = __hip_atomic_load(&src[tid], __ATOMIC_RELAXED,
                               __HIP_MEMORY_SCOPE_AGENT);
      if (!b1)
        v1 = __hip_atomic_load(&src[tid + NTHR], __ATOMIC_RELAXED,
                               __HIP_MEMORY_SCOPE_AGENT);
    }
    lds_hf[lp * HDIM + tid] = __uint_as_float((unsigned)v0);
    lds_hf[lp * HDIM + tid + NTHR] = __uint_as_float((unsigned)v1);
    if (tid < EDIM) lds_x[lp][tid] = xv;
    __syncthreads();

    // ---- gate pre-activation: x-projection folded into the same reduction
    float acc = lds_wih[row][sub] * lds_x[lp][sub];
    if (sub < EDIM - 8) acc += lds_wih[row][sub + 8] * lds_x[lp][sub + 8];
    if (sub == 0) acc += lds_bsum[row];
#pragma unroll
    for (int i = 0; i < 32; ++i) {
      float4 hv = lds_h4[lp][sub * 32 + ((i + sub) & 31)];
      float4 wv = wreg[i];
      acc += wv.x * hv.x;
      acc += wv.y * hv.y;
      acc += wv.z * hv.z;
      acc += wv.w * hv.w;
    }
    acc += __shfl_xor(acc, 1);
    acc += __shfl_xor(acc, 2);
    acc += __shfl_xor(acc, 4);

    // ---- activations computed in parallel on all lanes (one exp chain)
    float e = __expf(-gsc * acc);
    float y = 1.f / (1.f + e);
    float act = (g == 2) ? 2.f * y - 1.f : y;

    int base = lane & 32;
    float ai = __shfl(act, base + 0);
    float af = __shfl(act, base + 8);
    float ag = __shfl(act, base + 16);
    float ao = __shfl(act, base + 24);
    if ((lane & 31) == 0) {
      cst = af * cst + ai * ag;
      float e2 = __expf(-2.f * cst);
      float hn = ao * (2.f / (1.f + e2) - 1.f);
      ull pk = ((ull)(unsigned)t << 32) | (ull)__float_as_uint(hn);
      __hip_atomic_store(&hrec[(size_t)(t & 3) * HDIM + w * 16 + 2 * wave +
                               (lane >> 5)],
                         pk, __ATOMIC_RELAXED, __HIP_MEMORY_SCOPE_AGENT);
    }
    // no end-of-step barrier: publish is self-validating; LDS buffer reuse is
    // two steps away and ordered by the intervening step's __syncthreads.
  }

  // ---- tail step 1: u = tanh(W1 @ h_T + b1), 8 rows per WG --------------
  {
    // h_T: tag TSTEPS lives in ring parity (TSTEPS & 3) == 0
    const unsigned want = (unsigned)TSTEPS;
    ull v0 = __hip_atomic_load(&hrec[tid], __ATOMIC_RELAXED,
                               __HIP_MEMORY_SCOPE_AGENT);
    ull v1 = __hip_atomic_load(&hrec[tid + NTHR], __ATOMIC_RELAXED,
                               __HIP_MEMORY_SCOPE_AGENT);
    for (;;) {
      bool b0 = (unsigned)(v0 >> 32) == want;
      bool b1 = (unsigned)(v1 >> 32) == want;
      if (b0 && b1) break;
      if (!b0)
        v0 = __hip_atomic_load(&hrec[tid], __ATOMIC_RELAXED,
                               __HIP_MEMORY_SCOPE_AGENT);
      if (!b1)
        v1 = __hip_atomic_load(&hrec[tid + NTHR], __ATOMIC_RELAXED,
                               __HIP_MEMORY_SCOPE_AGENT);
    }
    lds_hf[tid] = __uint_as_float((unsigned)v0);
    lds_hf[tid + NTHR] = __uint_as_float((unsigned)v1);
  }
  __syncthreads();
  {
    int r1 = 8 * w + wave;  // one MLP row per wave
    const float* w1p = W1 + (size_t)r1 * HDIM + lane * 16;
    float acc1 = 0.f;
#pragma unroll
    for (int i = 0; i < 16; ++i) acc1 += w1p[i] * lds_hf[lane * 16 + i];
#pragma unroll
    for (int m = 1; m < 64; m <<= 1) acc1 += __shfl_xor(acc1, m);
    if (lane == 0) {
      float e2 = __expf(-2.f * (acc1 + b1[r1]));
      float u = 2.f / (1.f + e2) - 1.f;
      ull pk = (1ull << 32) | (ull)__float_as_uint(u);
      __hip_atomic_store(&urec[r1], pk, __ATOMIC_RELAXED,
                         __HIP_MEMORY_SCOPE_AGENT);
    }
  }

  // ---- tail step 2: out = W2 @ u + b2, WG 0 only -------------------------
  if (w == 0) {
    ull uv = __hip_atomic_load(&urec[tid], __ATOMIC_RELAXED,
                               __HIP_MEMORY_SCOPE_AGENT);
    while ((unsigned)(uv >> 32) != 1u)
      uv = __hip_atomic_load(&urec[tid], __ATOMIC_RELAXED,
                             __HIP_MEMORY_SCOPE_AGENT);
    float u = __uint_as_float((unsigned)uv);
    float p0 = W2[tid] * u;
    float p1 = W2[HLDIM + tid] * u;
#pragma unroll
    for (int m = 1; m < 64; m <<= 1) {
      p0 += __shfl_xor(p0, m);
      p1 += __shfl_xor(p1, m);
    }
    if (lane == 0) {
      lds_r0[wave] = p0;
      lds_r1[wave] = p1;
    }
    __syncthreads();
    if (tid == 0) {
      float o0 = b2[0], o1 = b2[1];
#pragma unroll
      for (int k = 0; k < 8; ++k) {
        o0 += lds_r0[k];
        o1 += lds_r1[k];
      }
      out[0] = o0;
      out[1] = o1;
    }
  }
}

extern "C" void kernel_launch(void* const* d_in, const int* in_sizes, int n_in,
                              void* d_out, int out_size, void* d_ws,
                              size_t ws_size, hipStream_t stream) {
  const float* x = (const float*)d_in[0];
  const float* h0 = (const float*)d_in[1];
  const float* c0 = (const float*)d_in[2];
  const float* Wih = (const float*)d_in[3];
  const float* Whh = (const float*)d_in[4];
  const float* bih = (const float*)d_in[5];
  const float* bhh = (const float*)d_in[6];
  const float* W1 = (const float*)d_in[7];
  const float* b1 = (const float*)d_in[8];
  const float* W2 = (const float*)d_in[9];
  const float* b2 = (const float*)d_in[10];
  float* out = (float*)d_out;

  ull* hrec = (ull*)d_ws;                                    // 4*1024*8 = 32 KB
  ull* urec = (ull*)((char*)d_ws + 4 * HDIM * sizeof(ull));  // 4 KB

  k_init<<<1, 1024, 0, stream>>>(h0, hrec, urec);
  k_main<<<NWG, NTHR, 0, stream>>>(x, c0, Wih, Whh, bih, bhh, W1, b1, W2, b2,
                                   out, hrec, urec);
}

// Round 4
// 49309.937 us; speedup vs baseline: 1.4680x; 1.0468x over previous
//
#include <hip/hip_runtime.h>
#include <cstdint>
#include <cstddef>

#define NWG 64
#define NTHR 512
#define TSTEPS 16384
#define HDIM 1024
#define EDIM 13
#define HLDIM 512

typedef unsigned long long ull;

// ---------------------------------------------------------------------------
// Init kernel: re-arm the tagged h-record ring and u-record every call (d_ws
// is poisoned once with 0xAA and never re-poisoned between graph replays; a
// finished replay also leaves end-state tags behind, so every tag word must
// be rewritten each launch).
// hrec[parity][i] = { low32: f32 h value, high32: u32 step tag }, 4 parities.
// ---------------------------------------------------------------------------
__global__ void k_init(const float* __restrict__ h0, ull* __restrict__ hrec,
                       ull* __restrict__ urec) {
  int i = threadIdx.x;
  hrec[i] = (ull)__float_as_uint(h0[i]);  // {h0, tag=0}
  hrec[HDIM + i] = 0ull;
  hrec[2 * HDIM + i] = 0ull;
  hrec[3 * HDIM + i] = 0ull;
  if (i < HLDIM) urec[i] = 0ull;
}

// ---------------------------------------------------------------------------
// Persistent LSTM kernel. 64 WGs x 512 threads, one WG per CU.
// WG w owns hidden units [16w, 16w+16) -> 64 gate rows of W_hh held in VGPRs
// (128 floats/thread).
// Round-3 failure mode: __launch_bounds__(512,2) only sets MIN waves/EU; the
// allocator chased 5 waves/EU (VGPR_Count=88) and spilled all of wreg to
// scratch (FETCH_SIZE tripled). amdgpu_waves_per_eu(2,2) clamps occupancy to
// exactly 2 waves/EU from BOTH sides -> full 256-VGPR budget, no spill
// incentive.
// Cross-WG sync: each hidden unit is a self-validating {value, tag} 8-byte
// chunk in a 4-deep parity ring, moved with relaxed agent-scope 64-bit
// atomics (single-copy atomic, serviced at the coherent point -> immune to
// non-coherent per-XCD L2s). One MALL round trip + one __syncthreads a step.
// ---------------------------------------------------------------------------
__global__ __launch_bounds__(NTHR)
__attribute__((amdgpu_waves_per_eu(2, 2))) void k_main(
    const float* __restrict__ x, const float* __restrict__ c0,
    const float* __restrict__ Wih, const float* __restrict__ Whh,
    const float* __restrict__ bih, const float* __restrict__ bhh,
    const float* __restrict__ W1, const float* __restrict__ b1,
    const float* __restrict__ W2, const float* __restrict__ b2,
    float* __restrict__ out, ull* hrec, ull* urec) {
  const int w = blockIdx.x;
  const int tid = threadIdx.x;
  const int sub = tid & 7;    // col-chunk index within row (8 x 128 cols)
  const int row = tid >> 3;   // local gate row 0..63
  const int wave = tid >> 6;  // 0..7
  const int lane = tid & 63;
  const int g = row & 3;      // 0=i 1=f 2=g 3=o
  const int lu = row >> 2;    // local unit 0..15
  const int grow = g * HDIM + w * 16 + lu;  // global gate row (gate-major)

  __shared__ float4 lds_h4[2][HDIM / 4];  // double-buffered by step parity
  __shared__ float lds_x[2][16];
  __shared__ float lds_wih[64][17];  // stride 17: conflict-free owner reads
  __shared__ float lds_bsum[64];
  __shared__ float lds_r0[8], lds_r1[8];
  float* lds_hf = (float*)lds_h4;  // [2][1024] flat

  // ---- load this thread's W_hh chunk, rotated so the wave's 8 distinct LDS
  // b128 addresses at compute time cover all 32 banks (conflict-free, 8-way
  // same-address broadcast within each sub group).
  float4 wreg[32];
  const float4* wrow = (const float4*)(Whh + (size_t)grow * HDIM) + sub * 32;
#pragma unroll
  for (int i = 0; i < 32; ++i) wreg[i] = wrow[(i + sub) & 31];
  // Pin in VGPRs: the asm claims to rewrite each value, so the compiler can
  // neither rematerialize the global loads nor fold them into the loop.
#pragma unroll
  for (int i = 0; i < 32; ++i)
    asm volatile("" : "+v"(wreg[i].x), "+v"(wreg[i].y), "+v"(wreg[i].z),
                     "+v"(wreg[i].w));

  if (tid < 64) {
    int g2 = tid & 3, lu2 = tid >> 2;
    int gr2 = g2 * HDIM + w * 16 + lu2;
#pragma unroll
    for (int e = 0; e < EDIM; ++e) lds_wih[tid][e] = Wih[gr2 * EDIM + e];
    lds_bsum[tid] = bih[gr2] + bhh[gr2];
  }
  // cell state: lanes 0 and 32 of each wave own units 2*wave and 2*wave+1
  float cst = c0[w * 16 + 2 * wave + (lane >> 5)];
  __syncthreads();

  const float gsc = (g == 2) ? 2.f : 1.f;  // tanh via 2*sigmoid(2x)-1

  for (int t = 1; t <= TSTEPS; ++t) {
    const int lp = (t - 1) & 1;  // LDS parity (2-deep, barrier-separated)
    // ---- x_t prefetch: issue before the poll so its latency hides there
    float xv = 0.f;
    if (tid < EDIM) xv = x[(size_t)(t - 1) * EDIM + tid];

    // ---- poll this thread's two {h, tag} chunks of h_{t-1}; the poll load
    // IS the data load (one MALL round trip). 4-deep ring: overwrite of a
    // tag-t chunk (by tag t+4) needs three cross-WG dependence chains of
    // separation -> overwrite-before-read unreachable.
    const ull* src = hrec + (size_t)((t - 1) & 3) * HDIM;
    const unsigned want = (unsigned)(t - 1);
    ull v0 = __hip_atomic_load(&src[tid], __ATOMIC_RELAXED,
                               __HIP_MEMORY_SCOPE_AGENT);
    ull v1 = __hip_atomic_load(&src[tid + NTHR], __ATOMIC_RELAXED,
                               __HIP_MEMORY_SCOPE_AGENT);
    for (;;) {
      bool b0 = (unsigned)(v0 >> 32) == want;
      bool b1 = (unsigned)(v1 >> 32) == want;
      if (b0 && b1) break;
      if (!b0)
        v0 = __hip_atomic_load(&src[tid], __ATOMIC_RELAXED,
                               __HIP_MEMORY_SCOPE_AGENT);
      if (!b1)
        v1 = __hip_atomic_load(&src[tid + NTHR], __ATOMIC_RELAXED,
                               __HIP_MEMORY_SCOPE_AGENT);
    }
    lds_hf[lp * HDIM + tid] = __uint_as_float((unsigned)v0);
    lds_hf[lp * HDIM + tid + NTHR] = __uint_as_float((unsigned)v1);
    if (tid < EDIM) lds_x[lp][tid] = xv;
    __syncthreads();

    // ---- gate pre-activation: x-projection folded into the same reduction
    float acc = lds_wih[row][sub] * lds_x[lp][sub];
    if (sub < EDIM - 8) acc += lds_wih[row][sub + 8] * lds_x[lp][sub + 8];
    if (sub == 0) acc += lds_bsum[row];
#pragma unroll
    for (int i = 0; i < 32; ++i) {
      float4 hv = lds_h4[lp][sub * 32 + ((i + sub) & 31)];
      float4 wv = wreg[i];
      acc += wv.x * hv.x;
      acc += wv.y * hv.y;
      acc += wv.z * hv.z;
      acc += wv.w * hv.w;
    }
    acc += __shfl_xor(acc, 1);
    acc += __shfl_xor(acc, 2);
    acc += __shfl_xor(acc, 4);

    // ---- activations computed in parallel on all lanes (one exp chain)
    float e = __expf(-gsc * acc);
    float y = 1.f / (1.f + e);
    float act = (g == 2) ? 2.f * y - 1.f : y;

    int base = lane & 32;
    float ai = __shfl(act, base + 0);
    float af = __shfl(act, base + 8);
    float ag = __shfl(act, base + 16);
    float ao = __shfl(act, base + 24);
    if ((lane & 31) == 0) {
      cst = af * cst + ai * ag;
      float e2 = __expf(-2.f * cst);
      float hn = ao * (2.f / (1.f + e2) - 1.f);
      ull pk = ((ull)(unsigned)t << 32) | (ull)__float_as_uint(hn);
      __hip_atomic_store(&hrec[(size_t)(t & 3) * HDIM + w * 16 + 2 * wave +
                               (lane >> 5)],
                         pk, __ATOMIC_RELAXED, __HIP_MEMORY_SCOPE_AGENT);
    }
    // no end-of-step barrier: publish is self-validating; LDS buffer reuse is
    // two steps away and ordered by the intervening step's __syncthreads.
  }

  // ---- tail step 1: u = tanh(W1 @ h_T + b1), 8 rows per WG --------------
  {
    // h_T: tag TSTEPS lives in ring parity (TSTEPS & 3) == 0
    const unsigned want = (unsigned)TSTEPS;
    ull v0 = __hip_atomic_load(&hrec[tid], __ATOMIC_RELAXED,
                               __HIP_MEMORY_SCOPE_AGENT);
    ull v1 = __hip_atomic_load(&hrec[tid + NTHR], __ATOMIC_RELAXED,
                               __HIP_MEMORY_SCOPE_AGENT);
    for (;;) {
      bool b0 = (unsigned)(v0 >> 32) == want;
      bool b1 = (unsigned)(v1 >> 32) == want;
      if (b0 && b1) break;
      if (!b0)
        v0 = __hip_atomic_load(&hrec[tid], __ATOMIC_RELAXED,
                               __HIP_MEMORY_SCOPE_AGENT);
      if (!b1)
        v1 = __hip_atomic_load(&hrec[tid + NTHR], __ATOMIC_RELAXED,
                               __HIP_MEMORY_SCOPE_AGENT);
    }
    lds_hf[tid] = __uint_as_float((unsigned)v0);
    lds_hf[tid + NTHR] = __uint_as_float((unsigned)v1);
  }
  __syncthreads();
  {
    int r1 = 8 * w + wave;  // one MLP row per wave
    const float* w1p = W1 + (size_t)r1 * HDIM + lane * 16;
    float acc1 = 0.f;
#pragma unroll
    for (int i = 0; i < 16; ++i) acc1 += w1p[i] * lds_hf[lane * 16 + i];
#pragma unroll
    for (int m = 1; m < 64; m <<= 1) acc1 += __shfl_xor(acc1, m);
    if (lane == 0) {
      float e2 = __expf(-2.f * (acc1 + b1[r1]));
      float u = 2.f / (1.f + e2) - 1.f;
      ull pk = (1ull << 32) | (ull)__float_as_uint(u);
      __hip_atomic_store(&urec[r1], pk, __ATOMIC_RELAXED,
                         __HIP_MEMORY_SCOPE_AGENT);
    }
  }

  // ---- tail step 2: out = W2 @ u + b2, WG 0 only -------------------------
  if (w == 0) {
    ull uv = __hip_atomic_load(&urec[tid], __ATOMIC_RELAXED,
                               __HIP_MEMORY_SCOPE_AGENT);
    while ((unsigned)(uv >> 32) != 1u)
      uv = __hip_atomic_load(&urec[tid], __ATOMIC_RELAXED,
                             __HIP_MEMORY_SCOPE_AGENT);
    float u = __uint_as_float((unsigned)uv);
    float p0 = W2[tid] * u;
    float p1 = W2[HLDIM + tid] * u;
#pragma unroll
    for (int m = 1; m < 64; m <<= 1) {
      p0 += __shfl_xor(p0, m);
      p1 += __shfl_xor(p1, m);
    }
    if (lane == 0) {
      lds_r0[wave] = p0;
      lds_r1[wave] = p1;
    }
    __syncthreads();
    if (tid == 0) {
      float o0 = b2[0], o1 = b2[1];
#pragma unroll
      for (int k = 0; k < 8; ++k) {
        o0 += lds_r0[k];
        o1 += lds_r1[k];
      }
      out[0] = o0;
      out[1] = o1;
    }
  }
}

extern "C" void kernel_launch(void* const* d_in, const int* in_sizes, int n_in,
                              void* d_out, int out_size, void* d_ws,
                              size_t ws_size, hipStream_t stream) {
  const float* x = (const float*)d_in[0];
  const float* h0 = (const float*)d_in[1];
  const float* c0 = (const float*)d_in[2];
  const float* Wih = (const float*)d_in[3];
  const float* Whh = (const float*)d_in[4];
  const float* bih = (const float*)d_in[5];
  const float* bhh = (const float*)d_in[6];
  const float* W1 = (const float*)d_in[7];
  const float* b1 = (const float*)d_in[8];
  const float* W2 = (const float*)d_in[9];
  const float* b2 = (const float*)d_in[10];
  float* out = (float*)d_out;

  ull* hrec = (ull*)d_ws;                                    // 4*1024*8 = 32 KB
  ull* urec = (ull*)((char*)d_ws + 4 * HDIM * sizeof(ull));  // 4 KB

  k_init<<<1, 1024, 0, stream>>>(h0, hrec, urec);
  k_main<<<NWG, NTHR, 0, stream>>>(x, c0, Wih, Whh, bih, bhh, W1, b1, W2, b2,
                                   out, hrec, urec);
}